// Round 12
// baseline (691.558 us; speedup 1.0000x reference)
//
#include <hip/hip_runtime.h>
#include <stdint.h>

// Problem dims (fixed by reference setup_inputs)
#define B_   32
#define T_   2048
#define I_   512
#define H_   16
#define D_   64
#define BT   (B_*T_)        // 65536 rows
#define CCH  64             // chunks per (b,h) chain
#define LCH  (T_/CCH)       // 32 timesteps per chunk

// GEMM col layout (3072 cols of Wt):
//   cols h*128 + d        : k of head h  -> consumed in-epilogue (scores)
//   cols h*128 + 64 + d   : q of head h  -> consumed in-epilogue
//   cols 2048 + h*64 + d  : v of head h  -> written to Vb head-major [b][h][t][d]

typedef short short8 __attribute__((ext_vector_type(8)));
typedef float floatx4 __attribute__((ext_vector_type(4)));

__device__ __forceinline__ unsigned short f2bf(float f) {
    uint32_t u = __float_as_uint(f);
    u = (u + 0x7FFFu + ((u >> 16) & 1u)) >> 16;   // RNE
    return (unsigned short)u;
}
__device__ __forceinline__ float bf2f(unsigned short u) {
    return __uint_as_float(((uint32_t)u) << 16);
}

// ---------------- Pass 0a: x fp32 -> bf16 ----------------
__global__ __launch_bounds__(256) void k_convert_x(const float* __restrict__ x,
                                                   unsigned short* __restrict__ xb) {
    int i = blockIdx.x * 256 + threadIdx.x;        // over n/4 exactly
    float4 v = ((const float4*)x)[i];
    ushort4 o;
    o.x = f2bf(v.x); o.y = f2bf(v.y); o.z = f2bf(v.z); o.w = f2bf(v.w);
    ((ushort4*)xb)[i] = o;
}

// ---------------- Pass 0b: W (I,H,D,3) fp32 -> Wt (3072 x 512) bf16, head-paired repack ----------------
__global__ __launch_bounds__(256) void k_repack_w(const float* __restrict__ W,
                                                  unsigned short* __restrict__ Wt) {
    int idx = blockIdx.x * 256 + threadIdx.x;      // over I*H*D*3
    if (idx >= I_ * H_ * D_ * 3) return;
    int kk = idx % 3;                              // 0=k, 1=v, 2=q
    int d  = (idx / 3) % D_;
    int h  = (idx / (3 * D_)) % H_;
    int i  = idx / (3 * D_ * H_);
    int col = (kk == 1) ? (2048 + h * 64 + d)
                        : (h * 128 + d + (kk == 2 ? 64 : 0));
    Wt[(size_t)col * I_ + i] = f2bf(W[idx]);
}

// ---------------- Pass 1: GEMM (BK=32, fragment-major LDS) with fused q.k scores ----------------
// LDS chunk index (fragidx*16 + l15), fragidx = rowgrp*4 + ks, holds
// global (row = rowgrp*16 + l15, k = k0 + ks*8 .. +8). Fragment ds_read_b128:
// lane(kh,l15) reads chunk (rowgrp*4+kh)*16+l15 -> 64 distinct consecutive 16B
// chunks per wave = conflict-free, addresses are base + const + l15*16.
__device__ __forceinline__ void load_lds16(const void* g, void* l) {
    __builtin_amdgcn_global_load_lds((const __attribute__((address_space(1))) unsigned int*)g,
                                     (__attribute__((address_space(3))) unsigned int*)l, 16, 0, 0);
}

__global__ __launch_bounds__(256) void k_gemm(const unsigned short* __restrict__ A,
                                              const unsigned short* __restrict__ Bt,
                                              unsigned short* __restrict__ Vb,
                                              float* __restrict__ s_arr) {
    __shared__ unsigned short Alds[128 * 32];   // 8 KB, fragment-major
    __shared__ unsigned short Blds[128 * 32];   // 8 KB
    const int tid  = threadIdx.x;
    const int lane = tid & 63;
    const int wave = tid >> 6;
    const int cb = blockIdx.x;                  // 0..15 score(head cb), 16..23 v
    const int rb = blockIdx.y;                  // 0..511
    const int l15 = lane & 15;
    const int kh  = lane >> 4;                  // 0..3

    if (cb < 16) {
        // ---- score block: 4 waves x (32 rows x 128 cols), acc[m<2][n<8] ----
        floatx4 acc[2][8] = {};
        for (int ko = 0; ko < 16; ++ko) {
            const int k0 = ko * 32;
            #pragma unroll
            for (int it = 0; it < 2; ++it) {
                int c = it * 256 + tid;         // chunk index 0..511
                int fragidx = c >> 4;
                int l15c = c & 15;
                int rowgrp = fragidx >> 2;
                int ks = fragidx & 3;
                load_lds16(A  + (size_t)(rb * 128 + rowgrp * 16 + l15c) * I_ + k0 + ks * 8,
                           (void*)(Alds + (size_t)(it * 256 + wave * 64) * 8));
                load_lds16(Bt + (size_t)(cb * 128 + rowgrp * 16 + l15c) * I_ + k0 + ks * 8,
                           (void*)(Blds + (size_t)(it * 256 + wave * 64) * 8));
            }
            __syncthreads();
            short8 af[2], bfr[8];
            #pragma unroll
            for (int m = 0; m < 2; ++m)
                af[m] = *(const short8*)(Alds + (size_t)(wave * 2 + m) * 512 + kh * 128 + l15 * 8);
            #pragma unroll
            for (int n = 0; n < 8; ++n)
                bfr[n] = *(const short8*)(Blds + (size_t)n * 512 + kh * 128 + l15 * 8);
            #pragma unroll
            for (int m = 0; m < 2; ++m)
                #pragma unroll
                for (int n = 0; n < 8; ++n)
                    acc[m][n] = __builtin_amdgcn_mfma_f32_16x16x32_bf16(af[m], bfr[n], acc[m][n], 0, 0, 0);
            __syncthreads();
        }
        // fused s = sum_d k[r,d]*q[r,d]: frag n pairs with frag n+4 (same d = n*16+l15)
        float sacc[2][4];
        #pragma unroll
        for (int m = 0; m < 2; ++m)
            #pragma unroll
            for (int reg = 0; reg < 4; ++reg) {
                float s = 0.f;
                #pragma unroll
                for (int n = 0; n < 4; ++n)
                    s += acc[m][n][reg] * acc[m][n + 4][reg];
                sacc[m][reg] = s;
            }
        #pragma unroll
        for (int m = 0; m < 2; ++m)
            #pragma unroll
            for (int reg = 0; reg < 4; ++reg) {
                float s = sacc[m][reg];
                s += __shfl_xor(s, 1);
                s += __shfl_xor(s, 2);
                s += __shfl_xor(s, 4);
                s += __shfl_xor(s, 8);
                sacc[m][reg] = s;
            }
        float sv = sacc[0][0];
        #pragma unroll
        for (int m = 0; m < 2; ++m)
            #pragma unroll
            for (int reg = 0; reg < 4; ++reg)
                if (l15 == m * 4 + reg) sv = sacc[m][reg];
        if (l15 < 8) {
            int row = rb * 128 + wave * 32 + (l15 >> 2) * 16 + kh * 4 + (l15 & 3);
            int b = row >> 11, t = row & 2047;
            s_arr[((size_t)(b * H_ + cb) << 11) + t] = sv;
        }
    } else {
        // ---- v block: 2x2 waves x (64x64), acc[4][4]; write head-major Vb ----
        const int wr = wave >> 1, wc = wave & 1;
        floatx4 acc[4][4] = {};
        for (int ko = 0; ko < 16; ++ko) {
            const int k0 = ko * 32;
            #pragma unroll
            for (int it = 0; it < 2; ++it) {
                int c = it * 256 + tid;
                int fragidx = c >> 4;
                int l15c = c & 15;
                int rowgrp = fragidx >> 2;
                int ks = fragidx & 3;
                load_lds16(A  + (size_t)(rb * 128 + rowgrp * 16 + l15c) * I_ + k0 + ks * 8,
                           (void*)(Alds + (size_t)(it * 256 + wave * 64) * 8));
                load_lds16(Bt + (size_t)(cb * 128 + rowgrp * 16 + l15c) * I_ + k0 + ks * 8,
                           (void*)(Blds + (size_t)(it * 256 + wave * 64) * 8));
            }
            __syncthreads();
            short8 af[4], bfr[4];
            #pragma unroll
            for (int m = 0; m < 4; ++m)
                af[m] = *(const short8*)(Alds + (size_t)(wr * 4 + m) * 512 + kh * 128 + l15 * 8);
            #pragma unroll
            for (int n = 0; n < 4; ++n)
                bfr[n] = *(const short8*)(Blds + (size_t)(wc * 4 + n) * 512 + kh * 128 + l15 * 8);
            #pragma unroll
            for (int m = 0; m < 4; ++m)
                #pragma unroll
                for (int n = 0; n < 4; ++n)
                    acc[m][n] = __builtin_amdgcn_mfma_f32_16x16x32_bf16(af[m], bfr[n], acc[m][n], 0, 0, 0);
            __syncthreads();
        }
        // head-major write: h = (cb-16)*2 + wc, d = n*16+l15, t = local row
        const int b_idx = rb >> 4;
        const int h = (cb - 16) * 2 + wc;
        const int t0 = (rb & 15) * 128 + wr * 64 + kh * 4;
        #pragma unroll
        for (int m = 0; m < 4; ++m) {
            #pragma unroll
            for (int n = 0; n < 4; ++n) {
                int d = n * 16 + l15;
                size_t base = ((size_t)(b_idx * H_ + h) * T_ + t0 + m * 16) * 64 + d;
                #pragma unroll
                for (int reg = 0; reg < 4; ++reg)
                    Vb[base + (size_t)reg * 64] = f2bf(acc[m][n][reg]);
            }
        }
    }
}

// ---------------- Pass 2: chunk summaries (vectorized short8 v-loads) ----------------
__global__ __launch_bounds__(256) void k_sumchunk(const unsigned short* __restrict__ Vb,
                                                  const float* __restrict__ s_arr,
                                                  float* __restrict__ m_arr,
                                                  float* __restrict__ d_arr,
                                                  float* __restrict__ n_arr) {
    const int wave = threadIdx.x >> 6, lane = threadIdx.x & 63;
    const int chunk = blockIdx.x * 4 + wave;     // = bh*64 + c
    const int c  = chunk & (CCH - 1);
    const int bh = chunk >> 6;
    const int tg = lane >> 3, g8 = lane & 7;

    float sval = (lane < 32) ? s_arr[(size_t)bh * T_ + c * LCH + lane] : -INFINITY;
    float M = sval;
    #pragma unroll
    for (int off = 32; off; off >>= 1) M = fmaxf(M, __shfl_xor(M, off));
    float wt_l = (lane < 32) ? __expf(sval - M) : 0.f;
    float Dh = wt_l;
    #pragma unroll
    for (int off = 32; off; off >>= 1) Dh += __shfl_xor(Dh, off);

    // Nh[d] = sum_t w_t * v[t][d]; lane covers d = g8*8..+8, t = {i*8+tg}
    float Nh[8] = {};
    size_t vbase = ((size_t)bh * T_ + c * LCH) * 64;
    #pragma unroll
    for (int i = 0; i < 4; ++i) {
        short8 v8 = *(const short8*)(Vb + vbase + (size_t)(i * 64 + lane) * 8);
        float w = __shfl(wt_l, i * 8 + tg);
        #pragma unroll
        for (int j = 0; j < 8; ++j) Nh[j] += w * bf2f((unsigned short)v8[j]);
    }
    #pragma unroll
    for (int off = 8; off < 64; off <<= 1)
        #pragma unroll
        for (int j = 0; j < 8; ++j) Nh[j] += __shfl_xor(Nh[j], off);

    if (lane == 0) { m_arr[chunk] = M; d_arr[chunk] = Dh; }
    if (lane < 8) {
        float4 a = {Nh[0], Nh[1], Nh[2], Nh[3]};
        float4 bq = {Nh[4], Nh[5], Nh[6], Nh[7]};
        *(float4*)(n_arr + (size_t)chunk * 64 + lane * 8)     = a;
        *(float4*)(n_arr + (size_t)chunk * 64 + lane * 8 + 4) = bq;
    }
}

// ---------------- Pass 3: exclusive prefix over chunks; fixed-normalizer prefix terms ----------------
__global__ __launch_bounds__(256) void k_prefix2(const float* __restrict__ m_arr,
                                                 const float* __restrict__ d_arr,
                                                 const float* __restrict__ n_arr,
                                                 float* __restrict__ Zb,
                                                 float* __restrict__ pdb,
                                                 float* __restrict__ pnb) {
    const int wave = threadIdx.x >> 6, lane = threadIdx.x & 63;
    const int bh = blockIdx.x * 4 + wave;        // 0..511
    float m = -INFINITY, den = 0.f, n = 0.f;
    for (int c = 0; c < CCH; ++c) {
        int idx = bh * CCH + c;
        float mc = m_arr[idx], dc = d_arr[idx];
        float nc = n_arr[(size_t)idx * 64 + lane];
        float Z = fmaxf(m, mc);
        float beta = __expf(m - Z);
        if (lane == 0) { Zb[idx] = Z; pdb[idx] = den * beta; }
        pnb[(size_t)idx * 64 + lane] = n * beta;
        float a2 = __expf(mc - Z);
        den = den * beta + dc * a2;
        n   = n * beta + nc * a2;
        m = Z;
    }
}

// ---------------- Pass 4: final — vectorized loads, log-depth prefix, LDS tree-sum ----------------
__global__ __launch_bounds__(256) void k_final(const unsigned short* __restrict__ Vb,
                                               const float* __restrict__ s_arr,
                                               const float* __restrict__ Zb,
                                               const float* __restrict__ pdb,
                                               const float* __restrict__ pnb,
                                               float* __restrict__ out) {
    __shared__ float red[4][LCH * 64];           // 32 KB
    const int tid = threadIdx.x;
    const int wave = tid >> 6, lane = tid & 63;
    const int tg = lane >> 3, g8 = lane & 7;
    const int bc = blockIdx.x;                   // b*64 + c
    const int c = bc & (CCH - 1), b = bc >> 6;

    float acc[4][8] = {};                        // [load i][j] -> (t=i*8+tg, d=g8*8+j)

    #pragma unroll
    for (int hh = 0; hh < 4; ++hh) {
        const int h = wave * 4 + hh;
        const int bh = b * H_ + h;
        const int chain = bh * CCH + c;
        const float Z  = Zb[chain];
        const float pd = pdb[chain];
        float4 p0 = *(const float4*)(pnb + (size_t)chain * 64 + g8 * 8);
        float4 p1 = *(const float4*)(pnb + (size_t)chain * 64 + g8 * 8 + 4);
        float pn8[8] = {p0.x, p0.y, p0.z, p0.w, p1.x, p1.y, p1.z, p1.w};

        float sval = (lane < 32) ? s_arr[(size_t)bh * T_ + c * LCH + lane] : 0.f;
        float wv = (lane < 32) ? __expf(sval - Z) : 0.f;
        float cum = wv;
        #pragma unroll
        for (int off = 1; off < 32; off <<= 1) {
            float o = __shfl_up(cum, off, 32);
            if ((lane & 31) >= off) cum += o;
        }
        float rv = __builtin_amdgcn_rcpf(pd + cum);  // 1/den_t on lane t

        float carry[8] = {};
        size_t vbase = ((size_t)bh * T_ + c * LCH) * 64;
        #pragma unroll
        for (int i = 0; i < 4; ++i) {
            short8 v8 = *(const short8*)(Vb + vbase + (size_t)(i * 64 + lane) * 8);
            float w = __shfl(wv, i * 8 + tg);
            float r = __shfl(rv, i * 8 + tg);
            float val[8];
            #pragma unroll
            for (int j = 0; j < 8; ++j) val[j] = w * bf2f((unsigned short)v8[j]);
            // inclusive prefix over tg (stride-8 lane groups)
            #pragma unroll
            for (int off = 8; off < 64; off <<= 1) {
                #pragma unroll
                for (int j = 0; j < 8; ++j) {
                    float o = __shfl_up(val[j], off);
                    if (lane >= off) val[j] += o;
                }
            }
            #pragma unroll
            for (int j = 0; j < 8; ++j)
                acc[i][j] += (pn8[j] + carry[j] + val[j]) * r;
            #pragma unroll
            for (int j = 0; j < 8; ++j)
                carry[j] += __shfl(val[j], 56 + g8);   // load total (tg=7)
        }
    }

    // stage per-wave results, then 4-way cross-wave sum
    #pragma unroll
    for (int i = 0; i < 4; ++i) {
        float4 a = {acc[i][0], acc[i][1], acc[i][2], acc[i][3]};
        float4 bq = {acc[i][4], acc[i][5], acc[i][6], acc[i][7]};
        *(float4*)(&red[wave][(i * 8 + tg) * 64 + g8 * 8])     = a;
        *(float4*)(&red[wave][(i * 8 + tg) * 64 + g8 * 8 + 4]) = bq;
    }
    __syncthreads();

    size_t ob = ((size_t)b * T_ + c * LCH) * 64;
    #pragma unroll
    for (int i = 0; i < 8; ++i) {
        int idx = i * 256 + tid;
        out[ob + idx] = red[0][idx] + red[1][idx] + red[2][idx] + red[3][idx];
    }
}

// ---------------- launch ----------------
extern "C" void kernel_launch(void* const* d_in, const int* in_sizes, int n_in,
                              void* d_out, int out_size, void* d_ws, size_t ws_size,
                              hipStream_t stream) {
    const float* x = (const float*)d_in[0];
    const float* W = (const float*)d_in[1];
    float* out = (float*)d_out;
    char* ws = (char*)d_ws;

    // workspace layout (bytes)
    unsigned short* Vb  = (unsigned short*)(ws);                 // 134,217,728
    unsigned short* xb  = (unsigned short*)(ws + 134217728ull);  //  67,108,864
    unsigned short* Wt  = (unsigned short*)(ws + 201326592ull);  //   3,145,728
    float* s_arr = (float*)(ws + 204472320ull);                  //   4,194,304
    float* m_arr = (float*)(ws + 208666624ull);                  //     131,072
    float* d_arr = (float*)(ws + 208797696ull);                  //     131,072
    float* n_arr = (float*)(ws + 208928768ull);                  //   8,388,608
    float* Zb    = (float*)(ws + 217317376ull);                  //     131,072
    float* pdb   = (float*)(ws + 217448448ull);                  //     131,072
    float* pnb   = (float*)(ws + 217579520ull);                  //   8,388,608 -> end 225,968,128

    k_convert_x<<<(BT * I_ / 4) / 256, 256, 0, stream>>>(x, xb);
    k_repack_w<<<(I_ * H_ * D_ * 3 + 255) / 256, 256, 0, stream>>>(W, Wt);
    k_gemm<<<dim3(24, BT / 128), 256, 0, stream>>>(xb, Wt, Vb, s_arr);
    k_sumchunk<<<(B_ * H_ * CCH) / 4, 256, 0, stream>>>(Vb, s_arr, m_arr, d_arr, n_arr);
    k_prefix2<<<(B_ * H_) / 4, 256, 0, stream>>>(m_arr, d_arr, n_arr, Zb, pdb, pnb);
    k_final<<<B_ * CCH, 256, 0, stream>>>(Vb, s_arr, Zb, pdb, pnb, out);
}

// Round 13
// 567.929 us; speedup vs baseline: 1.2177x; 1.2177x over previous
//
#include <hip/hip_runtime.h>
#include <stdint.h>

// Problem dims (fixed by reference setup_inputs)
#define B_   32
#define T_   2048
#define I_   512
#define H_   16
#define D_   64
#define BT   (B_*T_)        // 65536 rows
#define CCH  64             // chunks per (b,h) chain
#define LCH  (T_/CCH)       // 32 timesteps per chunk

// GEMM col layout (3072 cols of Wt):
//   cols h*128 + d        : k of head h  -> consumed in-epilogue (scores)
//   cols h*128 + 64 + d   : q of head h  -> consumed in-epilogue
//   cols 2048 + h*64 + d  : v of head h  -> written to Vb head-major [b][h][t][d]

typedef short short8 __attribute__((ext_vector_type(8)));
typedef float floatx4 __attribute__((ext_vector_type(4)));

__device__ __forceinline__ unsigned short f2bf(float f) {
    uint32_t u = __float_as_uint(f);
    u = (u + 0x7FFFu + ((u >> 16) & 1u)) >> 16;   // RNE
    return (unsigned short)u;
}
__device__ __forceinline__ float bf2f(unsigned short u) {
    return __uint_as_float(((uint32_t)u) << 16);
}

// ---------------- Pass 0a: x fp32 -> bf16 ----------------
__global__ __launch_bounds__(256) void k_convert_x(const float* __restrict__ x,
                                                   unsigned short* __restrict__ xb) {
    int i = blockIdx.x * 256 + threadIdx.x;        // over n/4 exactly
    float4 v = ((const float4*)x)[i];
    ushort4 o;
    o.x = f2bf(v.x); o.y = f2bf(v.y); o.z = f2bf(v.z); o.w = f2bf(v.w);
    ((ushort4*)xb)[i] = o;
}

// ---------------- Pass 0b: W (I,H,D,3) fp32 -> Wt (3072 x 512) bf16, head-paired repack ----------------
__global__ __launch_bounds__(256) void k_repack_w(const float* __restrict__ W,
                                                  unsigned short* __restrict__ Wt) {
    int idx = blockIdx.x * 256 + threadIdx.x;      // over I*H*D*3
    if (idx >= I_ * H_ * D_ * 3) return;
    int kk = idx % 3;                              // 0=k, 1=v, 2=q
    int d  = (idx / 3) % D_;
    int h  = (idx / (3 * D_)) % H_;
    int i  = idx / (3 * D_ * H_);
    int col = (kk == 1) ? (2048 + h * 64 + d)
                        : (h * 128 + d + (kk == 2 ? 64 : 0));
    Wt[(size_t)col * I_ + i] = f2bf(W[idx]);
}

// ---------------- Pass 1: GEMM (round-8 structure: BK=32, row-major LDS, coalesced staging)
//                  + bijective XCD swizzle + fused q.k scores + head-major Vb ----------------
__device__ __forceinline__ void load_lds16(const void* g, void* l) {
    __builtin_amdgcn_global_load_lds((const __attribute__((address_space(1))) unsigned int*)g,
                                     (__attribute__((address_space(3))) unsigned int*)l, 16, 0, 0);
}

__global__ __launch_bounds__(256) void k_gemm(const unsigned short* __restrict__ A,
                                              const unsigned short* __restrict__ Bt,
                                              unsigned short* __restrict__ Vb,
                                              float* __restrict__ s_arr) {
    __shared__ unsigned short Alds[128 * 32];   // 8 KB, row-major [row][k]
    __shared__ unsigned short Blds[128 * 32];   // 8 KB
    const int tid  = threadIdx.x;
    const int lane = tid & 63;
    const int wave = tid >> 6;
    // XCD-bijective swizzle: 12288 blocks = 8 XCDs x 1536. Each XCD gets a
    // contiguous swz range -> contiguous rb run x all 24 cb -> A-tiles L2-resident.
    const int bid = blockIdx.x;
    const int swz = (bid & 7) * 1536 + (bid >> 3);
    const int cb  = swz % 24;                   // 0..15 score(head cb), 16..23 v
    const int rb  = swz / 24;                   // 0..511
    const int l15 = lane & 15;
    const int kh  = lane >> 4;                  // 0..3

    if (cb < 16) {
        // ---- score block: 4 waves x (32 rows x 128 cols), acc[m<2][n<8] ----
        floatx4 acc[2][8] = {};
        for (int ko = 0; ko < 16; ++ko) {
            const int k0 = ko * 32;
            #pragma unroll
            for (int it = 0; it < 2; ++it) {
                int lin = it * 256 + wave * 64 + lane;
                int r = lin >> 2;               // row within tile
                int c = (lin & 3) << 3;         // k within BK
                load_lds16(A  + (size_t)(rb * 128 + r) * I_ + k0 + c,
                           (void*)(Alds + (size_t)(it * 256 + wave * 64) * 8));
                load_lds16(Bt + (size_t)(cb * 128 + r) * I_ + k0 + c,
                           (void*)(Blds + (size_t)(it * 256 + wave * 64) * 8));
            }
            __syncthreads();
            short8 af[2], bfr[8];
            #pragma unroll
            for (int m = 0; m < 2; ++m)
                af[m] = *(const short8*)(Alds + (size_t)(wave * 32 + m * 16 + l15) * 32 + kh * 8);
            #pragma unroll
            for (int n = 0; n < 8; ++n)
                bfr[n] = *(const short8*)(Blds + (size_t)(n * 16 + l15) * 32 + kh * 8);
            #pragma unroll
            for (int m = 0; m < 2; ++m)
                #pragma unroll
                for (int n = 0; n < 8; ++n)
                    acc[m][n] = __builtin_amdgcn_mfma_f32_16x16x32_bf16(af[m], bfr[n], acc[m][n], 0, 0, 0);
            __syncthreads();
        }
        // fused s = sum_d k[r,d]*q[r,d]: frag n pairs with frag n+4 (same d = n*16+l15)
        float sacc[2][4];
        #pragma unroll
        for (int m = 0; m < 2; ++m)
            #pragma unroll
            for (int reg = 0; reg < 4; ++reg) {
                float s = 0.f;
                #pragma unroll
                for (int n = 0; n < 4; ++n)
                    s += acc[m][n][reg] * acc[m][n + 4][reg];
                sacc[m][reg] = s;
            }
        #pragma unroll
        for (int m = 0; m < 2; ++m)
            #pragma unroll
            for (int reg = 0; reg < 4; ++reg) {
                float s = sacc[m][reg];
                s += __shfl_xor(s, 1);
                s += __shfl_xor(s, 2);
                s += __shfl_xor(s, 4);
                s += __shfl_xor(s, 8);
                sacc[m][reg] = s;
            }
        float sv = sacc[0][0];
        #pragma unroll
        for (int m = 0; m < 2; ++m)
            #pragma unroll
            for (int reg = 0; reg < 4; ++reg)
                if (l15 == m * 4 + reg) sv = sacc[m][reg];
        if (l15 < 8) {
            int row = rb * 128 + wave * 32 + (l15 >> 2) * 16 + kh * 4 + (l15 & 3);
            int b = row >> 11, t = row & 2047;
            s_arr[((size_t)(b * H_ + cb) << 11) + t] = sv;
        }
    } else {
        // ---- v block: 2x2 waves x (64x64), acc[4][4]; write head-major Vb ----
        const int wr = wave >> 1, wc = wave & 1;
        floatx4 acc[4][4] = {};
        for (int ko = 0; ko < 16; ++ko) {
            const int k0 = ko * 32;
            #pragma unroll
            for (int it = 0; it < 2; ++it) {
                int lin = it * 256 + wave * 64 + lane;
                int r = lin >> 2;
                int c = (lin & 3) << 3;
                load_lds16(A  + (size_t)(rb * 128 + r) * I_ + k0 + c,
                           (void*)(Alds + (size_t)(it * 256 + wave * 64) * 8));
                load_lds16(Bt + (size_t)(cb * 128 + r) * I_ + k0 + c,
                           (void*)(Blds + (size_t)(it * 256 + wave * 64) * 8));
            }
            __syncthreads();
            short8 af[4], bfr[4];
            #pragma unroll
            for (int m = 0; m < 4; ++m)
                af[m] = *(const short8*)(Alds + (size_t)(wr * 64 + m * 16 + l15) * 32 + kh * 8);
            #pragma unroll
            for (int n = 0; n < 4; ++n)
                bfr[n] = *(const short8*)(Blds + (size_t)(wc * 64 + n * 16 + l15) * 32 + kh * 8);
            #pragma unroll
            for (int m = 0; m < 4; ++m)
                #pragma unroll
                for (int n = 0; n < 4; ++n)
                    acc[m][n] = __builtin_amdgcn_mfma_f32_16x16x32_bf16(af[m], bfr[n], acc[m][n], 0, 0, 0);
            __syncthreads();
        }
        // head-major write: h = (cb-16)*2 + wc, d = n*16+l15, t = local row
        const int b_idx = rb >> 4;
        const int h = (cb - 16) * 2 + wc;
        const int t0 = (rb & 15) * 128 + wr * 64 + kh * 4;
        #pragma unroll
        for (int m = 0; m < 4; ++m) {
            #pragma unroll
            for (int n = 0; n < 4; ++n) {
                int d = n * 16 + l15;
                size_t base = ((size_t)(b_idx * H_ + h) * T_ + t0 + m * 16) * 64 + d;
                #pragma unroll
                for (int reg = 0; reg < 4; ++reg)
                    Vb[base + (size_t)reg * 64] = f2bf(acc[m][n][reg]);
            }
        }
    }
}

// ---------------- Pass 2: chunk summaries (vectorized short8 v-loads) ----------------
__global__ __launch_bounds__(256) void k_sumchunk(const unsigned short* __restrict__ Vb,
                                                  const float* __restrict__ s_arr,
                                                  float* __restrict__ m_arr,
                                                  float* __restrict__ d_arr,
                                                  float* __restrict__ n_arr) {
    const int wave = threadIdx.x >> 6, lane = threadIdx.x & 63;
    const int chunk = blockIdx.x * 4 + wave;     // = bh*64 + c
    const int c  = chunk & (CCH - 1);
    const int bh = chunk >> 6;
    const int tg = lane >> 3, g8 = lane & 7;

    float sval = (lane < 32) ? s_arr[(size_t)bh * T_ + c * LCH + lane] : -INFINITY;
    float M = sval;
    #pragma unroll
    for (int off = 32; off; off >>= 1) M = fmaxf(M, __shfl_xor(M, off));
    float wt_l = (lane < 32) ? __expf(sval - M) : 0.f;
    float Dh = wt_l;
    #pragma unroll
    for (int off = 32; off; off >>= 1) Dh += __shfl_xor(Dh, off);

    // Nh[d] = sum_t w_t * v[t][d]; lane covers d = g8*8..+8, t = {i*8+tg}
    float Nh[8] = {};
    size_t vbase = ((size_t)bh * T_ + c * LCH) * 64;
    #pragma unroll
    for (int i = 0; i < 4; ++i) {
        short8 v8 = *(const short8*)(Vb + vbase + (size_t)(i * 64 + lane) * 8);
        float w = __shfl(wt_l, i * 8 + tg);
        #pragma unroll
        for (int j = 0; j < 8; ++j) Nh[j] += w * bf2f((unsigned short)v8[j]);
    }
    #pragma unroll
    for (int off = 8; off < 64; off <<= 1)
        #pragma unroll
        for (int j = 0; j < 8; ++j) Nh[j] += __shfl_xor(Nh[j], off);

    if (lane == 0) { m_arr[chunk] = M; d_arr[chunk] = Dh; }
    if (lane < 8) {
        float4 a = {Nh[0], Nh[1], Nh[2], Nh[3]};
        float4 bq = {Nh[4], Nh[5], Nh[6], Nh[7]};
        *(float4*)(n_arr + (size_t)chunk * 64 + lane * 8)     = a;
        *(float4*)(n_arr + (size_t)chunk * 64 + lane * 8 + 4) = bq;
    }
}

// ---------------- Pass 3: exclusive prefix over chunks; fixed-normalizer prefix terms ----------------
__global__ __launch_bounds__(256) void k_prefix2(const float* __restrict__ m_arr,
                                                 const float* __restrict__ d_arr,
                                                 const float* __restrict__ n_arr,
                                                 float* __restrict__ Zb,
                                                 float* __restrict__ pdb,
                                                 float* __restrict__ pnb) {
    const int wave = threadIdx.x >> 6, lane = threadIdx.x & 63;
    const int bh = blockIdx.x * 4 + wave;        // 0..511
    float m = -INFINITY, den = 0.f, n = 0.f;
    for (int c = 0; c < CCH; ++c) {
        int idx = bh * CCH + c;
        float mc = m_arr[idx], dc = d_arr[idx];
        float nc = n_arr[(size_t)idx * 64 + lane];
        float Z = fmaxf(m, mc);
        float beta = __expf(m - Z);
        if (lane == 0) { Zb[idx] = Z; pdb[idx] = den * beta; }
        pnb[(size_t)idx * 64 + lane] = n * beta;
        float a2 = __expf(mc - Z);
        den = den * beta + dc * a2;
        n   = n * beta + nc * a2;
        m = Z;
    }
}

// ---------------- Pass 4: final — vectorized loads, log-depth prefix, LDS tree-sum ----------------
__global__ __launch_bounds__(256) void k_final(const unsigned short* __restrict__ Vb,
                                               const float* __restrict__ s_arr,
                                               const float* __restrict__ Zb,
                                               const float* __restrict__ pdb,
                                               const float* __restrict__ pnb,
                                               float* __restrict__ out) {
    __shared__ float red[4][LCH * 64];           // 32 KB
    const int tid = threadIdx.x;
    const int wave = tid >> 6, lane = tid & 63;
    const int tg = lane >> 3, g8 = lane & 7;
    const int bc = blockIdx.x;                   // b*64 + c
    const int c = bc & (CCH - 1), b = bc >> 6;

    float acc[4][8] = {};                        // [load i][j] -> (t=i*8+tg, d=g8*8+j)

    #pragma unroll
    for (int hh = 0; hh < 4; ++hh) {
        const int h = wave * 4 + hh;
        const int bh = b * H_ + h;
        const int chain = bh * CCH + c;
        const float Z  = Zb[chain];
        const float pd = pdb[chain];
        float4 p0 = *(const float4*)(pnb + (size_t)chain * 64 + g8 * 8);
        float4 p1 = *(const float4*)(pnb + (size_t)chain * 64 + g8 * 8 + 4);
        float pn8[8] = {p0.x, p0.y, p0.z, p0.w, p1.x, p1.y, p1.z, p1.w};

        float sval = (lane < 32) ? s_arr[(size_t)bh * T_ + c * LCH + lane] : 0.f;
        float wv = (lane < 32) ? __expf(sval - Z) : 0.f;
        float cum = wv;
        #pragma unroll
        for (int off = 1; off < 32; off <<= 1) {
            float o = __shfl_up(cum, off, 32);
            if ((lane & 31) >= off) cum += o;
        }
        float rv = __builtin_amdgcn_rcpf(pd + cum);  // 1/den_t on lane t

        float carry[8] = {};
        size_t vbase = ((size_t)bh * T_ + c * LCH) * 64;
        #pragma unroll
        for (int i = 0; i < 4; ++i) {
            short8 v8 = *(const short8*)(Vb + vbase + (size_t)(i * 64 + lane) * 8);
            float w = __shfl(wv, i * 8 + tg);
            float r = __shfl(rv, i * 8 + tg);
            float val[8];
            #pragma unroll
            for (int j = 0; j < 8; ++j) val[j] = w * bf2f((unsigned short)v8[j]);
            // inclusive prefix over tg (stride-8 lane groups)
            #pragma unroll
            for (int off = 8; off < 64; off <<= 1) {
                #pragma unroll
                for (int j = 0; j < 8; ++j) {
                    float o = __shfl_up(val[j], off);
                    if (lane >= off) val[j] += o;
                }
            }
            #pragma unroll
            for (int j = 0; j < 8; ++j)
                acc[i][j] += (pn8[j] + carry[j] + val[j]) * r;
            #pragma unroll
            for (int j = 0; j < 8; ++j)
                carry[j] += __shfl(val[j], 56 + g8);   // load total (tg=7)
        }
    }

    // stage per-wave results, then 4-way cross-wave sum
    #pragma unroll
    for (int i = 0; i < 4; ++i) {
        float4 a = {acc[i][0], acc[i][1], acc[i][2], acc[i][3]};
        float4 bq = {acc[i][4], acc[i][5], acc[i][6], acc[i][7]};
        *(float4*)(&red[wave][(i * 8 + tg) * 64 + g8 * 8])     = a;
        *(float4*)(&red[wave][(i * 8 + tg) * 64 + g8 * 8 + 4]) = bq;
    }
    __syncthreads();

    size_t ob = ((size_t)b * T_ + c * LCH) * 64;
    #pragma unroll
    for (int i = 0; i < 8; ++i) {
        int idx = i * 256 + tid;
        out[ob + idx] = red[0][idx] + red[1][idx] + red[2][idx] + red[3][idx];
    }
}

// ---------------- launch ----------------
extern "C" void kernel_launch(void* const* d_in, const int* in_sizes, int n_in,
                              void* d_out, int out_size, void* d_ws, size_t ws_size,
                              hipStream_t stream) {
    const float* x = (const float*)d_in[0];
    const float* W = (const float*)d_in[1];
    float* out = (float*)d_out;
    char* ws = (char*)d_ws;

    // workspace layout (bytes)
    unsigned short* Vb  = (unsigned short*)(ws);                 // 134,217,728
    unsigned short* xb  = (unsigned short*)(ws + 134217728ull);  //  67,108,864
    unsigned short* Wt  = (unsigned short*)(ws + 201326592ull);  //   3,145,728
    float* s_arr = (float*)(ws + 204472320ull);                  //   4,194,304
    float* m_arr = (float*)(ws + 208666624ull);                  //     131,072
    float* d_arr = (float*)(ws + 208797696ull);                  //     131,072
    float* n_arr = (float*)(ws + 208928768ull);                  //   8,388,608
    float* Zb    = (float*)(ws + 217317376ull);                  //     131,072
    float* pdb   = (float*)(ws + 217448448ull);                  //     131,072
    float* pnb   = (float*)(ws + 217579520ull);                  //   8,388,608 -> end 225,968,128

    k_convert_x<<<(BT * I_ / 4) / 256, 256, 0, stream>>>(x, xb);
    k_repack_w<<<(I_ * H_ * D_ * 3 + 255) / 256, 256, 0, stream>>>(W, Wt);
    k_gemm<<<24 * (BT / 128), 256, 0, stream>>>(xb, Wt, Vb, s_arr);
    k_sumchunk<<<(B_ * H_ * CCH) / 4, 256, 0, stream>>>(Vb, s_arr, m_arr, d_arr, n_arr);
    k_prefix2<<<(B_ * H_) / 4, 256, 0, stream>>>(m_arr, d_arr, n_arr, Zb, pdb, pnb);
    k_final<<<B_ * CCH, 256, 0, stream>>>(Vb, s_arr, Zb, pdb, pnb, out);
}